// Round 1
// baseline (597.582 us; speedup 1.0000x reference)
//
#include <hip/hip_runtime.h>

// MultiHeadAttention: S=1024, B=4, D_MODEL=1024, H=16, DK=DV=64, D_OUT=1024
// Pipeline: cvt+transpose W (fp32->bf16, [k][n]->[n][k]) -> 3 proj GEMMs (bf16 MFMA,
// epilogue scatters to [h*4+b][s][d]) -> V transpose to [h*4+b][d][t] -> fused
// attention (QK^T -> softmax -> attn write + PV) -> out GEMM (fp32 epilogue).

typedef unsigned short u16;
typedef unsigned int u32;
typedef short short8v __attribute__((ext_vector_type(8)));   // 8 bf16 bits = 4 VGPRs
typedef float f32x4 __attribute__((ext_vector_type(4)));

__device__ __forceinline__ u16 f2bf(float f) {               // RNE fp32->bf16
    u32 u = __builtin_bit_cast(u32, f);
    u += 0x7fffu + ((u >> 16) & 1u);
    return (u16)(u >> 16);
}

__device__ __forceinline__ f32x4 mfma_bf16(short8v a, short8v b, f32x4 c) {
    return __builtin_amdgcn_mfma_f32_16x16x32_bf16(a, b, c, 0, 0, 0);
}

// ---- W[k][n] fp32 -> Wt[n][k] bf16 (1024x1024), grid 256 (16x16 tiles of 64) ----
__global__ __launch_bounds__(256) void cvt_transpose_w(const float* __restrict__ W,
                                                       u16* __restrict__ Wt) {
    __shared__ u16 T[64][72];                                // 72: 16B-aligned rows, bank-spread
    const int n0 = (blockIdx.x & 15) << 6;
    const int k0 = (blockIdx.x >> 4) << 6;
    const int t = threadIdx.x;
    const int r = t >> 2;
    const int c = t & 3;
    const float4* src = reinterpret_cast<const float4*>(W + (size_t)(k0 + r) * 1024 + n0 + c * 16);
#pragma unroll
    for (int j = 0; j < 4; ++j) {
        float4 v = src[j];
        T[c * 16 + j * 4 + 0][r] = f2bf(v.x);
        T[c * 16 + j * 4 + 1][r] = f2bf(v.y);
        T[c * 16 + j * 4 + 2][r] = f2bf(v.z);
        T[c * 16 + j * 4 + 3][r] = f2bf(v.w);
    }
    __syncthreads();
    u16* dst = Wt + (size_t)(n0 + r) * 1024 + k0 + c * 16;
    *reinterpret_cast<short8v*>(dst)     = *reinterpret_cast<const short8v*>(&T[r][c * 16]);
    *reinterpret_cast<short8v*>(dst + 8) = *reinterpret_cast<const short8v*>(&T[r][c * 16 + 8]);
}

// ---- GEMM: C(4096x1024) = A(4096x1024) @ Wt^T + bias ----
// AMODE 0: A fp32 (converted in staging); 1: A bf16.
// EMODE 0: bf16 out scattered to [h*4+b][s][d]; 1: fp32 out row-major [mi][c].
// 128x128 tile, BK=32, 256 threads (4 waves, 64x64 each). LDS stride 40 (80B) kills
// the stride-64B 8-way bank conflict on fragment reads (2-way residual, free).
template <int AMODE, int EMODE>
__global__ __launch_bounds__(256) void gemm_kernel(const void* __restrict__ A_,
                                                   const u16* __restrict__ Wt,
                                                   const float* __restrict__ bias,
                                                   void* __restrict__ dst_) {
    __shared__ u16 As[128][40];
    __shared__ u16 Bs[128][40];
    const int m0 = blockIdx.y << 7;
    const int n0 = blockIdx.x << 7;
    const int t = threadIdx.x;
    const int lane = t & 63;
    const int w = t >> 6;
    const int wr = (w >> 1) << 6;
    const int wc = (w & 1) << 6;
    const int l15 = lane & 15, lg = lane >> 4;
    const int srow = t >> 1;              // staging row 0..127
    const int shalf = (t & 1) << 4;       // k-half: 0 or 16

    f32x4 acc[4][4] = {};

    for (int k0 = 0; k0 < 1024; k0 += 32) {
        if (AMODE == 0) {
            const float* A = (const float*)A_;
            const float4* src = reinterpret_cast<const float4*>(A + (size_t)(m0 + srow) * 1024 + k0 + shalf);
            float4 v0 = src[0], v1 = src[1], v2 = src[2], v3 = src[3];
            short8v p0, p1;
            p0[0] = f2bf(v0.x); p0[1] = f2bf(v0.y); p0[2] = f2bf(v0.z); p0[3] = f2bf(v0.w);
            p0[4] = f2bf(v1.x); p0[5] = f2bf(v1.y); p0[6] = f2bf(v1.z); p0[7] = f2bf(v1.w);
            p1[0] = f2bf(v2.x); p1[1] = f2bf(v2.y); p1[2] = f2bf(v2.z); p1[3] = f2bf(v2.w);
            p1[4] = f2bf(v3.x); p1[5] = f2bf(v3.y); p1[6] = f2bf(v3.z); p1[7] = f2bf(v3.w);
            *reinterpret_cast<short8v*>(&As[srow][shalf])     = p0;
            *reinterpret_cast<short8v*>(&As[srow][shalf + 8]) = p1;
        } else {
            const u16* A = (const u16*)A_;
            const short8v* src = reinterpret_cast<const short8v*>(A + (size_t)(m0 + srow) * 1024 + k0 + shalf);
            *reinterpret_cast<short8v*>(&As[srow][shalf])     = src[0];
            *reinterpret_cast<short8v*>(&As[srow][shalf + 8]) = src[1];
        }
        {
            const short8v* src = reinterpret_cast<const short8v*>(Wt + (size_t)(n0 + srow) * 1024 + k0 + shalf);
            *reinterpret_cast<short8v*>(&Bs[srow][shalf])     = src[0];
            *reinterpret_cast<short8v*>(&Bs[srow][shalf + 8]) = src[1];
        }
        __syncthreads();
        short8v a[4], b[4];
#pragma unroll
        for (int m = 0; m < 4; ++m)
            a[m] = *reinterpret_cast<const short8v*>(&As[wr + m * 16 + l15][lg * 8]);
#pragma unroll
        for (int n = 0; n < 4; ++n)
            b[n] = *reinterpret_cast<const short8v*>(&Bs[wc + n * 16 + l15][lg * 8]);
#pragma unroll
        for (int m = 0; m < 4; ++m)
#pragma unroll
            for (int n = 0; n < 4; ++n)
                acc[m][n] = mfma_bf16(a[m], b[n], acc[m][n]);
        __syncthreads();
    }

#pragma unroll
    for (int n = 0; n < 4; ++n) {
        const int c = n0 + wc + n * 16 + l15;
        const float bv = bias[c];
#pragma unroll
        for (int m = 0; m < 4; ++m) {
#pragma unroll
            for (int r = 0; r < 4; ++r) {
                const int mi = m0 + wr + m * 16 + lg * 4 + r;
                const float val = acc[m][n][r] + bv;
                if (EMODE == 0) {
                    u16* dst = (u16*)dst_;
                    const int h = c >> 6, d = c & 63, s = mi >> 2, bb = mi & 3;
                    dst[(size_t)(((h << 2) + bb) << 16) + (s << 6) + d] = f2bf(val);
                } else {
                    float* dst = (float*)dst_;
                    dst[(size_t)mi * 1024 + c] = val;
                }
            }
        }
    }
}

// ---- V transpose: vb[hb][s][d] -> vtb[hb][d][s] (64 hb x 16 s-tiles) ----
__global__ __launch_bounds__(256) void transpose_v(const u16* __restrict__ vb,
                                                   u16* __restrict__ vtb) {
    __shared__ u16 T[64][72];
    const int hb = blockIdx.y;
    const int s0 = blockIdx.x << 6;
    const u16* src = vb + (size_t)hb * 65536;
    u16* dst = vtb + (size_t)hb * 65536;
    const int t = threadIdx.x;
    const int r = t >> 2;
    const int c = (t & 3) << 4;
    short8v v0 = *reinterpret_cast<const short8v*>(src + (size_t)(s0 + r) * 64 + c);
    short8v v1 = *reinterpret_cast<const short8v*>(src + (size_t)(s0 + r) * 64 + c + 8);
#pragma unroll
    for (int j = 0; j < 8; ++j) T[c + j][r] = (u16)v0[j];
#pragma unroll
    for (int j = 0; j < 8; ++j) T[c + 8 + j][r] = (u16)v1[j];
    __syncthreads();
    *reinterpret_cast<short8v*>(dst + (size_t)r * 1024 + s0 + c)     = *reinterpret_cast<const short8v*>(&T[r][c]);
    *reinterpret_cast<short8v*>(dst + (size_t)r * 1024 + s0 + c + 8) = *reinterpret_cast<const short8v*>(&T[r][c + 8]);
}

// ---- fused attention: per (hb, 32-row q-tile): QK^T -> softmax -> attn write + PV ----
// 512 threads (8 waves). Wave w owns t-strip [w*128, w*128+128). S tile 32x1024 fp32 in
// LDS (128 KB) with per-row rotation phys(c) = (c + 8*row) & 1023 to spread banks.
__global__ __launch_bounds__(512, 1) void attn_kernel(const u16* __restrict__ qb,
                                                      const u16* __restrict__ kb,
                                                      const u16* __restrict__ vtb,
                                                      float* __restrict__ attn_out,
                                                      u16* __restrict__ ctxb) {
    __shared__ float S[32 * 1024];
    const int hb = blockIdx.y;
    const int q0 = blockIdx.x << 5;
    const int h = hb >> 2, b = hb & 3;
    const int t = threadIdx.x;
    const int lane = t & 63, w = t >> 6;
    const int l15 = lane & 15, lg = lane >> 4;

    const u16* Q = qb + (size_t)hb * 65536;
    const u16* K = kb + (size_t)hb * 65536;
    const u16* VT = vtb + (size_t)hb * 65536;

    // QK^T (A = Q rows, B = K rows read as K^T cols; both contiguous-k 16B loads)
    short8v aq[2][2];
#pragma unroll
    for (int m = 0; m < 2; ++m)
#pragma unroll
        for (int kh = 0; kh < 2; ++kh)
            aq[m][kh] = *reinterpret_cast<const short8v*>(Q + (q0 + m * 16 + l15) * 64 + kh * 32 + lg * 8);

#pragma unroll
    for (int n = 0; n < 8; ++n) {
        const int tcol = w * 128 + n * 16 + l15;
        f32x4 s0acc = {}, s1acc = {};
#pragma unroll
        for (int kh = 0; kh < 2; ++kh) {
            short8v bk = *reinterpret_cast<const short8v*>(K + tcol * 64 + kh * 32 + lg * 8);
            s0acc = mfma_bf16(aq[0][kh], bk, s0acc);
            s1acc = mfma_bf16(aq[1][kh], bk, s1acc);
        }
#pragma unroll
        for (int r = 0; r < 4; ++r) {
            const int row0 = lg * 4 + r;
            const int row1 = 16 + row0;
            S[row0 * 1024 + ((tcol + row0 * 8) & 1023)] = s0acc[r] * 0.125f;
            S[row1 * 1024 + ((tcol + row1 * 8) & 1023)] = s1acc[r] * 0.125f;
        }
    }
    __syncthreads();

    // softmax: wave w owns rows 4w..4w+3; lane-strided cols -> conflict-free, full-wave reduce
#pragma unroll
    for (int rr = 0; rr < 4; ++rr) {
        const int r = w * 4 + rr;
        const int rot = r * 8;
        float v[16];
        float mx = -1e30f;
#pragma unroll
        for (int j = 0; j < 16; ++j) {
            v[j] = S[r * 1024 + ((j * 64 + lane + rot) & 1023)];
            mx = fmaxf(mx, v[j]);
        }
#pragma unroll
        for (int o = 1; o < 64; o <<= 1) mx = fmaxf(mx, __shfl_xor(mx, o, 64));
        float sum = 0.f;
#pragma unroll
        for (int j = 0; j < 16; ++j) { v[j] = __expf(v[j] - mx); sum += v[j]; }
#pragma unroll
        for (int o = 1; o < 64; o <<= 1) sum += __shfl_xor(sum, o, 64);
        const float inv = 1.0f / sum;
        float* grow = attn_out + (size_t)(hb * 1024 + q0 + r) * 1024;
#pragma unroll
        for (int j = 0; j < 16; ++j) {
            const float p = v[j] * inv;
            S[r * 1024 + ((j * 64 + lane + rot) & 1023)] = p;
            grow[j * 64 + lane] = p;
        }
    }
    __syncthreads();

    // PV: wave w accumulates its 128-t strip into a 32x64 partial
    f32x4 cacc[2][4] = {};
#pragma unroll
    for (int kt = 0; kt < 4; ++kt) {
        short8v ap[2];
#pragma unroll
        for (int m = 0; m < 2; ++m) {
            const int row = m * 16 + l15;
            const int col = (w * 128 + kt * 32 + lg * 8 + row * 8) & 1023;
            const f32x4 lo = *reinterpret_cast<const f32x4*>(&S[row * 1024 + col]);
            const f32x4 hi = *reinterpret_cast<const f32x4*>(&S[row * 1024 + col + 4]);
            short8v p;
#pragma unroll
            for (int j = 0; j < 4; ++j) { p[j] = (short)f2bf(lo[j]); p[4 + j] = (short)f2bf(hi[j]); }
            ap[m] = p;
        }
#pragma unroll
        for (int n = 0; n < 4; ++n) {
            short8v bv = *reinterpret_cast<const short8v*>(VT + (size_t)(n * 16 + l15) * 1024 + w * 128 + kt * 32 + lg * 8);
            cacc[0][n] = mfma_bf16(ap[0], bv, cacc[0][n]);
            cacc[1][n] = mfma_bf16(ap[1], bv, cacc[1][n]);
        }
    }
    __syncthreads();                      // S dead; reuse as partial buffer
    float* part = S;
#pragma unroll
    for (int m = 0; m < 2; ++m)
#pragma unroll
        for (int n = 0; n < 4; ++n)
#pragma unroll
            for (int r = 0; r < 4; ++r)
                part[(w * 32 + m * 16 + lg * 4 + r) * 64 + n * 16 + l15] = cacc[m][n][r];
    __syncthreads();
    {
        const int e = t * 4;
        const int rrow = e >> 6, col = e & 63;
        f32x4 sum4 = {};
#pragma unroll
        for (int ww = 0; ww < 8; ++ww)
            sum4 += *reinterpret_cast<const f32x4*>(&part[(ww * 32 + rrow) * 64 + col]);
        u16* dst = ctxb + (size_t)((q0 + rrow) * 4 + b) * 1024 + h * 64 + col;
        dst[0] = f2bf(sum4[0]); dst[1] = f2bf(sum4[1]); dst[2] = f2bf(sum4[2]); dst[3] = f2bf(sum4[3]);
    }
}

extern "C" void kernel_launch(void* const* d_in, const int* in_sizes, int n_in,
                              void* d_out, int out_size, void* d_ws, size_t ws_size,
                              hipStream_t stream) {
    const float* query = (const float*)d_in[0];
    const float* key   = (const float*)d_in[1];
    const float* value = (const float*)d_in[2];
    const float* Wq = (const float*)d_in[3];
    const float* bq = (const float*)d_in[4];
    const float* Wk = (const float*)d_in[5];
    const float* bk = (const float*)d_in[6];
    const float* Wv = (const float*)d_in[7];
    const float* bv = (const float*)d_in[8];
    const float* Wo = (const float*)d_in[9];
    const float* bo = (const float*)d_in[10];

    char* ws = (char*)d_ws;
    u16* Wtq  = (u16*)(ws);                       // 2 MB
    u16* Wtk  = (u16*)(ws + ((size_t)2 << 20));   // 2 MB
    u16* Wtv  = (u16*)(ws + ((size_t)4 << 20));   // 2 MB
    u16* Wto  = (u16*)(ws + ((size_t)6 << 20));   // 2 MB
    u16* qb   = (u16*)(ws + ((size_t)8 << 20));   // 8 MB  [hb][s][dk]
    u16* kb   = (u16*)(ws + ((size_t)16 << 20));  // 8 MB  [hb][t][dk]
    u16* vb   = (u16*)(ws + ((size_t)24 << 20));  // 8 MB  [hb][t][dv] (dead after transpose)
    u16* vtb  = (u16*)(ws + ((size_t)32 << 20));  // 8 MB  [hb][dv][t]
    u16* ctxb = (u16*)(ws + ((size_t)24 << 20));  // 8 MB  aliases vb (vb dead by then)

    float* out  = (float*)d_out;
    float* attn = out + (size_t)4 * 1024 * 1024;  // (H,B,S,S) fp32 region

    cvt_transpose_w<<<256, 256, 0, stream>>>(Wq, Wtq);
    cvt_transpose_w<<<256, 256, 0, stream>>>(Wk, Wtk);
    cvt_transpose_w<<<256, 256, 0, stream>>>(Wv, Wtv);
    cvt_transpose_w<<<256, 256, 0, stream>>>(Wo, Wto);

    gemm_kernel<0, 0><<<dim3(8, 32), 256, 0, stream>>>(query, Wtq, bq, qb);
    gemm_kernel<0, 0><<<dim3(8, 32), 256, 0, stream>>>(key,   Wtk, bk, kb);
    gemm_kernel<0, 0><<<dim3(8, 32), 256, 0, stream>>>(value, Wtv, bv, vb);

    transpose_v<<<dim3(16, 64), 256, 0, stream>>>(vb, vtb);

    attn_kernel<<<dim3(32, 64), 512, 0, stream>>>(qb, kb, vtb, attn, ctxb);

    gemm_kernel<1, 1><<<dim3(8, 32), 256, 0, stream>>>(ctxb, Wto, bo, out);
}

// Round 2
// 529.593 us; speedup vs baseline: 1.1284x; 1.1284x over previous
//
#include <hip/hip_runtime.h>

// MultiHeadAttention: S=1024, B=4, D_MODEL=1024, H=16, DK=DV=64, D_OUT=1024
// R2: occupancy-focused rewrite.
//  - one fused W-transpose launch (4 weights)
//  - one fused QKV projection GEMM (grid 768 = 3 blocks/CU), BK=64, reg-prefetch dbuf
//  - attn: 16-row tiles, 64KB LDS (2 blocks/CU), vectorized softmax IO, bf16 P in LDS,
//    XOR swizzle (row&7)<<4 on S/P rows
//  - out GEMM: in-block split-K (waves 0-3 k<512, waves 4-7 k>=512), LDS combine

typedef unsigned short u16;
typedef unsigned int u32;
typedef short short8v __attribute__((ext_vector_type(8)));   // 8 bf16 = 4 VGPRs
typedef short short4v __attribute__((ext_vector_type(4)));   // 4 bf16 = 2 VGPRs
typedef float f32x4 __attribute__((ext_vector_type(4)));

__device__ __forceinline__ u16 f2bf(float f) {               // RNE fp32->bf16
    u32 u = __builtin_bit_cast(u32, f);
    u += 0x7fffu + ((u >> 16) & 1u);
    return (u16)(u >> 16);
}

__device__ __forceinline__ f32x4 mfma_bf16(short8v a, short8v b, f32x4 c) {
    return __builtin_amdgcn_mfma_f32_16x16x32_bf16(a, b, c, 0, 0, 0);
}

// ---- 4x W[k][n] fp32 -> Wt[n][k] bf16 (1024x1024); grid (256, 4) ----
__global__ __launch_bounds__(256) void cvt_transpose_w4(const float* __restrict__ W0,
                                                        const float* __restrict__ W1,
                                                        const float* __restrict__ W2,
                                                        const float* __restrict__ W3,
                                                        u16* __restrict__ T0, u16* __restrict__ T1,
                                                        u16* __restrict__ T2, u16* __restrict__ T3) {
    __shared__ u16 T[64][72];
    const float* W; u16* Wt;
    switch (blockIdx.y) {
        case 0: W = W0; Wt = T0; break;
        case 1: W = W1; Wt = T1; break;
        case 2: W = W2; Wt = T2; break;
        default: W = W3; Wt = T3; break;
    }
    const int n0 = (blockIdx.x & 15) << 6;
    const int k0 = (blockIdx.x >> 4) << 6;
    const int t = threadIdx.x;
    const int r = t >> 2;
    const int c = t & 3;
    const float4* src = reinterpret_cast<const float4*>(W + (size_t)(k0 + r) * 1024 + n0 + c * 16);
#pragma unroll
    for (int j = 0; j < 4; ++j) {
        float4 v = src[j];
        T[c * 16 + j * 4 + 0][r] = f2bf(v.x);
        T[c * 16 + j * 4 + 1][r] = f2bf(v.y);
        T[c * 16 + j * 4 + 2][r] = f2bf(v.z);
        T[c * 16 + j * 4 + 3][r] = f2bf(v.w);
    }
    __syncthreads();
    u16* dst = Wt + (size_t)(n0 + r) * 1024 + k0 + c * 16;
    *reinterpret_cast<short8v*>(dst)     = *reinterpret_cast<const short8v*>(&T[r][c * 16]);
    *reinterpret_cast<short8v*>(dst + 8) = *reinterpret_cast<const short8v*>(&T[r][c * 16 + 8]);
}

// ---- fused QKV GEMM: C(4096x1024) = A_z @ Wt_z^T + b_z, bf16 scatter epilogue ----
// grid (8, 32, 3), 256 thr. BK=64, reg-prefetch double buffer.
__global__ __launch_bounds__(256, 2) void gemm_qkv(const float* __restrict__ Aq,
                                                   const float* __restrict__ Ak,
                                                   const float* __restrict__ Av,
                                                   const u16* __restrict__ Wtq,
                                                   const u16* __restrict__ Wtk,
                                                   const u16* __restrict__ Wtv,
                                                   const float* __restrict__ bq,
                                                   const float* __restrict__ bk,
                                                   const float* __restrict__ bv,
                                                   u16* __restrict__ dq, u16* __restrict__ dk,
                                                   u16* __restrict__ dv) {
    __shared__ u16 As[128][72];
    __shared__ u16 Bs[128][72];
    const float* A; const u16* Wt; const float* bias; u16* dst;
    switch (blockIdx.z) {
        case 0: A = Aq; Wt = Wtq; bias = bq; dst = dq; break;
        case 1: A = Ak; Wt = Wtk; bias = bk; dst = dk; break;
        default: A = Av; Wt = Wtv; bias = bv; dst = dv; break;
    }
    const int m0 = blockIdx.y << 7;
    const int n0 = blockIdx.x << 7;
    const int t = threadIdx.x;
    const int lane = t & 63;
    const int w = t >> 6;
    const int wr = (w >> 1) << 6;
    const int wc = (w & 1) << 6;
    const int l15 = lane & 15, lg = lane >> 4;
    const int srow = t >> 1;
    const int sh = (t & 1) << 5;          // k offset within 64: 0 or 32

    const float* Arow = A + (size_t)(m0 + srow) * 1024 + sh;
    const u16*   Brow = Wt + (size_t)(n0 + srow) * 1024 + sh;

    f32x4 acc[4][4] = {};
    float4 ra[8]; short8v rb[4];

    auto LOADR = [&](int kt) {
        const float4* ap = reinterpret_cast<const float4*>(Arow + kt * 64);
#pragma unroll
        for (int j = 0; j < 8; ++j) ra[j] = ap[j];
        const short8v* bp = reinterpret_cast<const short8v*>(Brow + kt * 64);
#pragma unroll
        for (int j = 0; j < 4; ++j) rb[j] = bp[j];
    };

    LOADR(0);
    for (int kt = 0; kt < 16; ++kt) {
        __syncthreads();
#pragma unroll
        for (int j = 0; j < 4; ++j) {
            float4 x = ra[2 * j], y = ra[2 * j + 1];
            short8v p;
            p[0] = (short)f2bf(x.x); p[1] = (short)f2bf(x.y);
            p[2] = (short)f2bf(x.z); p[3] = (short)f2bf(x.w);
            p[4] = (short)f2bf(y.x); p[5] = (short)f2bf(y.y);
            p[6] = (short)f2bf(y.z); p[7] = (short)f2bf(y.w);
            *reinterpret_cast<short8v*>(&As[srow][sh + j * 8]) = p;
            *reinterpret_cast<short8v*>(&Bs[srow][sh + j * 8]) = rb[j];
        }
        if (kt < 15) LOADR(kt + 1);
        __syncthreads();
#pragma unroll
        for (int kk = 0; kk < 2; ++kk) {
            short8v a[4], b[4];
#pragma unroll
            for (int m = 0; m < 4; ++m)
                a[m] = *reinterpret_cast<const short8v*>(&As[wr + m * 16 + l15][kk * 32 + lg * 8]);
#pragma unroll
            for (int n = 0; n < 4; ++n)
                b[n] = *reinterpret_cast<const short8v*>(&Bs[wc + n * 16 + l15][kk * 32 + lg * 8]);
#pragma unroll
            for (int m = 0; m < 4; ++m)
#pragma unroll
                for (int n = 0; n < 4; ++n)
                    acc[m][n] = mfma_bf16(a[m], b[n], acc[m][n]);
        }
    }

#pragma unroll
    for (int n = 0; n < 4; ++n) {
        const int c = n0 + wc + n * 16 + l15;
        const float bvv = bias[c];
        const int h = c >> 6, d = c & 63;
#pragma unroll
        for (int m = 0; m < 4; ++m) {
#pragma unroll
            for (int r = 0; r < 4; ++r) {
                const int mi = m0 + wr + m * 16 + lg * 4 + r;
                const int s = mi >> 2, bb = mi & 3;
                dst[(size_t)(((h << 2) + bb) << 16) + (s << 6) + d] = f2bf(acc[m][n][r] + bvv);
            }
        }
    }
}

// ---- V transpose: vb[hb][s][d] -> vtb[hb][d][s] ----
__global__ __launch_bounds__(256) void transpose_v(const u16* __restrict__ vb,
                                                   u16* __restrict__ vtb) {
    __shared__ u16 T[64][72];
    const int hb = blockIdx.y;
    const int s0 = blockIdx.x << 6;
    const u16* src = vb + (size_t)hb * 65536;
    u16* dst = vtb + (size_t)hb * 65536;
    const int t = threadIdx.x;
    const int r = t >> 2;
    const int c = (t & 3) << 4;
    short8v v0 = *reinterpret_cast<const short8v*>(src + (size_t)(s0 + r) * 64 + c);
    short8v v1 = *reinterpret_cast<const short8v*>(src + (size_t)(s0 + r) * 64 + c + 8);
#pragma unroll
    for (int j = 0; j < 8; ++j) T[c + j][r] = (u16)v0[j];
#pragma unroll
    for (int j = 0; j < 8; ++j) T[c + 8 + j][r] = (u16)v1[j];
    __syncthreads();
    *reinterpret_cast<short8v*>(dst + (size_t)r * 1024 + s0 + c)     = *reinterpret_cast<const short8v*>(&T[r][c]);
    *reinterpret_cast<short8v*>(dst + (size_t)r * 1024 + s0 + c + 8) = *reinterpret_cast<const short8v*>(&T[r][c + 8]);
}

// ---- fused attention: 16 q-rows per block, 512 thr (8 waves, 128-t strips) ----
// S logits fp32 [16][1024] in LDS (64KB), XOR swizzle (row&7)<<4 on byte addr.
// softmax: wave w owns rows 2w,2w+1; vectorized f32x4 LDS reads + float4 global writes;
// P written back as bf16 into first half of each S row; PV reads bf16 fragments directly.
__global__ __launch_bounds__(512, 4) void attn_kernel(const u16* __restrict__ qb,
                                                      const u16* __restrict__ kb,
                                                      const u16* __restrict__ vtb,
                                                      float* __restrict__ attn_out,
                                                      u16* __restrict__ ctxb) {
    __shared__ float Sm[16 * 1024];                          // 64 KB
    char* Sb = (char*)Sm;
    const int hb = blockIdx.y;
    const int q0 = blockIdx.x << 4;
    const int h = hb >> 2, b = hb & 3;
    const int t = threadIdx.x;
    const int lane = t & 63, w = t >> 6;
    const int l15 = lane & 15, lg = lane >> 4;

    const u16* Q = qb + (size_t)hb * 65536;
    const u16* K = kb + (size_t)hb * 65536;
    const u16* VT = vtb + (size_t)hb * 65536;

    // ---- QK^T ----
    short8v aq[2];
#pragma unroll
    for (int kh = 0; kh < 2; ++kh)
        aq[kh] = *reinterpret_cast<const short8v*>(Q + (q0 + l15) * 64 + kh * 32 + lg * 8);

#pragma unroll
    for (int n = 0; n < 8; ++n) {
        const int tcol = w * 128 + n * 16 + l15;
        f32x4 acc = {};
#pragma unroll
        for (int kh = 0; kh < 2; ++kh) {
            short8v bk = *reinterpret_cast<const short8v*>(K + tcol * 64 + kh * 32 + lg * 8);
            acc = mfma_bf16(aq[kh], bk, acc);
        }
#pragma unroll
        for (int r = 0; r < 4; ++r) {
            const int row = lg * 4 + r;
            *(float*)(Sb + (row << 12) + (((tcol) << 2) ^ ((row & 7) << 4))) = acc[r] * 0.125f;
        }
    }
    __syncthreads();

    // ---- softmax on rows 2w, 2w+1 ----
#pragma unroll
    for (int rr = 0; rr < 2; ++rr) {
        const int r = w * 2 + rr;
        const int swz = (r & 7) << 4;
        f32x4 vv[4];
#pragma unroll
        for (int j = 0; j < 4; ++j)
            vv[j] = *(const f32x4*)(Sb + (r << 12) + (((lane * 4 + j * 256) << 2) ^ swz));
        float mx = -1e30f;
#pragma unroll
        for (int j = 0; j < 4; ++j)
#pragma unroll
            for (int i = 0; i < 4; ++i) mx = fmaxf(mx, vv[j][i]);
#pragma unroll
        for (int o = 1; o < 64; o <<= 1) mx = fmaxf(mx, __shfl_xor(mx, o, 64));
        float sum = 0.f;
#pragma unroll
        for (int j = 0; j < 4; ++j)
#pragma unroll
            for (int i = 0; i < 4; ++i) { vv[j][i] = __expf(vv[j][i] - mx); sum += vv[j][i]; }
#pragma unroll
        for (int o = 1; o < 64; o <<= 1) sum += __shfl_xor(sum, o, 64);
        const float inv = 1.0f / sum;
        float* grow = attn_out + (((size_t)(hb << 10) + q0 + r) << 10);
#pragma unroll
        for (int j = 0; j < 4; ++j) {
            f32x4 p = vv[j] * inv;
            *reinterpret_cast<f32x4*>(grow + lane * 4 + j * 256) = p;
            short4v pk;
            pk[0] = (short)f2bf(p[0]); pk[1] = (short)f2bf(p[1]);
            pk[2] = (short)f2bf(p[2]); pk[3] = (short)f2bf(p[3]);
            *(short4v*)(Sb + (r << 12) + (((lane * 4 + j * 256) << 1) ^ swz)) = pk;
        }
    }
    __syncthreads();

    // ---- PV: wave w covers t in [w*128, w*128+128) ----
    f32x4 cacc[4] = {};
#pragma unroll
    for (int kt = 0; kt < 4; ++kt) {
        const int kcol = w * 128 + kt * 32 + lg * 8;
        short8v ap = *(const short8v*)(Sb + (l15 << 12) + (((kcol) << 1) ^ ((l15 & 7) << 4)));
#pragma unroll
        for (int n = 0; n < 4; ++n) {
            short8v bv = *reinterpret_cast<const short8v*>(VT + (size_t)(n * 16 + l15) * 1024 + kcol);
            cacc[n] = mfma_bf16(ap, bv, cacc[n]);
        }
    }
    __syncthreads();

    // ---- cross-wave partial reduce: part[w][16][68] ----
    float* part = Sm;
#pragma unroll
    for (int n = 0; n < 4; ++n)
#pragma unroll
        for (int r = 0; r < 4; ++r)
            part[w * 1088 + (lg * 4 + r) * 68 + n * 16 + l15] = cacc[n][r];
    __syncthreads();
    if (t < 256) {
        const int rrow = t >> 4;
        const int c0 = (t & 15) << 2;
        f32x4 s = {};
#pragma unroll
        for (int ww = 0; ww < 8; ++ww)
            s += *reinterpret_cast<const f32x4*>(&part[ww * 1088 + rrow * 68 + c0]);
        short4v o;
        o[0] = (short)f2bf(s[0]); o[1] = (short)f2bf(s[1]);
        o[2] = (short)f2bf(s[2]); o[3] = (short)f2bf(s[3]);
        *reinterpret_cast<short4v*>(ctxb + (size_t)(((q0 + rrow) << 2) + b) * 1024 + h * 64 + c0) = o;
    }
}

// ---- out GEMM with in-block split-K: 512 thr; grp0 k<512, grp1 k>=512; LDS combine ----
__global__ __launch_bounds__(512, 2) void gemm_out(const u16* __restrict__ ctxb,
                                                   const u16* __restrict__ Wto,
                                                   const float* __restrict__ bo,
                                                   float* __restrict__ out) {
    __shared__ char LB[73728];                               // 2 x (As+Bs) [128][72] u16
    const int m0 = blockIdx.y << 7;
    const int n0 = blockIdx.x << 7;
    const int t = threadIdx.x;
    const int lane = t & 63;
    const int w = t >> 6;
    const int grp = w >> 2;
    const int wl = w & 3;
    const int wr = (wl >> 1) << 6;
    const int wc = (wl & 1) << 6;
    const int l15 = lane & 15, lg = lane >> 4;
    const int tg = t & 255;
    const int srow = tg >> 1;
    const int sh = (tg & 1) << 5;

    u16 (*As)[72] = (u16(*)[72])(LB + grp * 36864);
    u16 (*Bs)[72] = (u16(*)[72])(LB + grp * 36864 + 18432);
    const int kb0 = grp << 9;

    const u16* Arow = ctxb + (size_t)(m0 + srow) * 1024 + kb0 + sh;
    const u16* Brow = Wto + (size_t)(n0 + srow) * 1024 + kb0 + sh;

    f32x4 acc[4][4] = {};
    short8v ra[4], rb[4];

    auto LOADR = [&](int s) {
        const short8v* ap = reinterpret_cast<const short8v*>(Arow + s * 64);
        const short8v* bp = reinterpret_cast<const short8v*>(Brow + s * 64);
#pragma unroll
        for (int j = 0; j < 4; ++j) { ra[j] = ap[j]; rb[j] = bp[j]; }
    };

    LOADR(0);
    for (int s = 0; s < 8; ++s) {
        __syncthreads();
#pragma unroll
        for (int j = 0; j < 4; ++j) {
            *reinterpret_cast<short8v*>(&As[srow][sh + j * 8]) = ra[j];
            *reinterpret_cast<short8v*>(&Bs[srow][sh + j * 8]) = rb[j];
        }
        if (s < 7) LOADR(s + 1);
        __syncthreads();
#pragma unroll
        for (int kk = 0; kk < 2; ++kk) {
            short8v a[4], b[4];
#pragma unroll
            for (int m = 0; m < 4; ++m)
                a[m] = *reinterpret_cast<const short8v*>(&As[wr + m * 16 + l15][kk * 32 + lg * 8]);
#pragma unroll
            for (int n = 0; n < 4; ++n)
                b[n] = *reinterpret_cast<const short8v*>(&Bs[wc + n * 16 + l15][kk * 32 + lg * 8]);
#pragma unroll
            for (int m = 0; m < 4; ++m)
#pragma unroll
                for (int n = 0; n < 4; ++n)
                    acc[m][n] = mfma_bf16(a[m], b[n], acc[m][n]);
        }
    }

    __syncthreads();
    float* part = (float*)LB;                                // [128][132] fp32
    if (grp == 1) {
#pragma unroll
        for (int m = 0; m < 4; ++m)
#pragma unroll
            for (int n = 0; n < 4; ++n)
#pragma unroll
                for (int r = 0; r < 4; ++r)
                    part[(wr + m * 16 + lg * 4 + r) * 132 + wc + n * 16 + l15] = acc[m][n][r];
    }
    __syncthreads();
    if (grp == 0) {
#pragma unroll
        for (int n = 0; n < 4; ++n) {
            const int c = n0 + wc + n * 16 + l15;
            const float bvv = bo[c];
#pragma unroll
            for (int m = 0; m < 4; ++m)
#pragma unroll
                for (int r = 0; r < 4; ++r) {
                    const int mi = m0 + wr + m * 16 + lg * 4 + r;
                    out[(size_t)mi * 1024 + c] =
                        acc[m][n][r] + part[(wr + m * 16 + lg * 4 + r) * 132 + wc + n * 16 + l15] + bvv;
                }
        }
    }
}

extern "C" void kernel_launch(void* const* d_in, const int* in_sizes, int n_in,
                              void* d_out, int out_size, void* d_ws, size_t ws_size,
                              hipStream_t stream) {
    const float* query = (const float*)d_in[0];
    const float* key   = (const float*)d_in[1];
    const float* value = (const float*)d_in[2];
    const float* Wq = (const float*)d_in[3];
    const float* bq = (const float*)d_in[4];
    const float* Wk = (const float*)d_in[5];
    const float* bk = (const float*)d_in[6];
    const float* Wv = (const float*)d_in[7];
    const float* bv = (const float*)d_in[8];
    const float* Wo = (const float*)d_in[9];
    const float* bo = (const float*)d_in[10];

    char* ws = (char*)d_ws;
    u16* Wtq  = (u16*)(ws);                       // 2 MB
    u16* Wtk  = (u16*)(ws + ((size_t)2 << 20));   // 2 MB
    u16* Wtv  = (u16*)(ws + ((size_t)4 << 20));   // 2 MB
    u16* Wto  = (u16*)(ws + ((size_t)6 << 20));   // 2 MB
    u16* qb   = (u16*)(ws + ((size_t)8 << 20));   // 8 MB  [hb][s][dk]
    u16* kb   = (u16*)(ws + ((size_t)16 << 20));  // 8 MB  [hb][t][dk]
    u16* vb   = (u16*)(ws + ((size_t)24 << 20));  // 8 MB  [hb][t][dv]
    u16* vtb  = (u16*)(ws + ((size_t)32 << 20));  // 8 MB  [hb][dv][t]
    u16* ctxb = (u16*)(ws + ((size_t)24 << 20));  // aliases vb (vb dead after transpose)

    float* out  = (float*)d_out;
    float* attn = out + (size_t)4 * 1024 * 1024;  // (H,B,S,S) fp32

    cvt_transpose_w4<<<dim3(256, 4), 256, 0, stream>>>(Wq, Wk, Wv, Wo, Wtq, Wtk, Wtv, Wto);

    gemm_qkv<<<dim3(8, 32, 3), 256, 0, stream>>>(query, key, value, Wtq, Wtk, Wtv,
                                                 bq, bk, bv, qb, kb, vb);

    transpose_v<<<dim3(16, 64), 256, 0, stream>>>(vb, vtb);

    attn_kernel<<<dim3(64, 64), 512, 0, stream>>>(qb, kb, vtb, attn, ctxb);

    gemm_out<<<dim3(8, 32), 512, 0, stream>>>(ctxb, Wto, bo, out);
}

// Round 6
// 504.505 us; speedup vs baseline: 1.1845x; 1.0497x over previous
//
#include <hip/hip_runtime.h>

// MultiHeadAttention: S=1024, B=4, D_MODEL=1024, H=16, DK=DV=64, D_OUT=1024
// R3 (3rd resubmit; three GPU acquisition timeouts — kernel has never been benched):
// GEMMs rebuilt on the m97 structure (global_load_lds width-16, BK=64,
// 2-barrier loop). All GEMM-staged buffers (bf16 inputs, transposed weights,
// attn ctx) stored chunk-XOR pre-swizzled (chunk ^= row&7 per 64-k tile) so
// linear gload_lds dest + XOR'd ds_read_b128 is bank-conflict-free.

typedef unsigned short u16;
typedef unsigned int u32;
typedef short short8v __attribute__((ext_vector_type(8)));   // 8 bf16 = 4 VGPRs
typedef short short4v __attribute__((ext_vector_type(4)));
typedef float f32x4 __attribute__((ext_vector_type(4)));

__device__ __forceinline__ u16 f2bf(float f) {               // RNE fp32->bf16
    u32 u = __builtin_bit_cast(u32, f);
    u += 0x7fffu + ((u >> 16) & 1u);
    return (u16)(u >> 16);
}
__device__ __forceinline__ f32x4 mfma_bf16(short8v a, short8v b, f32x4 c) {
    return __builtin_amdgcn_mfma_f32_16x16x32_bf16(a, b, c, 0, 0, 0);
}
__device__ __forceinline__ void gload16(const void* g, void* l) {
    __builtin_amdgcn_global_load_lds((const __attribute__((address_space(1))) u32*)g,
                                     (__attribute__((address_space(3))) u32*)l, 16, 0, 0);
}

// ---- fp32 -> bf16 input conversion with chunk swizzle; grid (2048, 3) ----
// out[row][ (tile<<3) | (ci ^ (row&7)) ] chunk = in chunk (tile,ci); chunk = 8 elems.
__global__ __launch_bounds__(256) void cvt_inputs(const float* __restrict__ X0,
                                                  const float* __restrict__ X1,
                                                  const float* __restrict__ X2,
                                                  u16* __restrict__ Y0, u16* __restrict__ Y1,
                                                  u16* __restrict__ Y2) {
    const float* X; u16* Y;
    switch (blockIdx.y) {
        case 0: X = X0; Y = Y0; break;
        case 1: X = X1; Y = Y1; break;
        default: X = X2; Y = Y2; break;
    }
    const int tid = blockIdx.x * 256 + threadIdx.x;      // [0, 524288)
    const int row = tid >> 7;
    const int c = tid & 127;                             // chunk in row
    const float4* s4 = reinterpret_cast<const float4*>(X + (size_t)row * 1024 + c * 8);
    float4 v0 = s4[0], v1 = s4[1];
    short8v p;
    p[0] = (short)f2bf(v0.x); p[1] = (short)f2bf(v0.y);
    p[2] = (short)f2bf(v0.z); p[3] = (short)f2bf(v0.w);
    p[4] = (short)f2bf(v1.x); p[5] = (short)f2bf(v1.y);
    p[6] = (short)f2bf(v1.z); p[7] = (short)f2bf(v1.w);
    const int dc = (c & ~7) | ((c ^ row) & 7);
    *reinterpret_cast<short8v*>(Y + (size_t)row * 1024 + dc * 8) = p;
}

// ---- 4x W[k][n] fp32 -> Wt[n][k] bf16, chunk-swizzled; grid (256, 4) ----
__global__ __launch_bounds__(256) void cvt_transpose_w4(const float* __restrict__ W0,
                                                        const float* __restrict__ W1,
                                                        const float* __restrict__ W2,
                                                        const float* __restrict__ W3,
                                                        u16* __restrict__ T0, u16* __restrict__ T1,
                                                        u16* __restrict__ T2, u16* __restrict__ T3) {
    __shared__ u16 T[64][72];
    const float* W; u16* Wt;
    switch (blockIdx.y) {
        case 0: W = W0; Wt = T0; break;
        case 1: W = W1; Wt = T1; break;
        case 2: W = W2; Wt = T2; break;
        default: W = W3; Wt = T3; break;
    }
    const int n0 = (blockIdx.x & 15) << 6;
    const int k0 = (blockIdx.x >> 4) << 6;
    const int t = threadIdx.x;
    const int r = t >> 2;
    const int c = t & 3;
    const float4* src = reinterpret_cast<const float4*>(W + (size_t)(k0 + r) * 1024 + n0 + c * 16);
#pragma unroll
    for (int j = 0; j < 4; ++j) {
        float4 v = src[j];
        T[c * 16 + j * 4 + 0][r] = f2bf(v.x);
        T[c * 16 + j * 4 + 1][r] = f2bf(v.y);
        T[c * 16 + j * 4 + 2][r] = f2bf(v.z);
        T[c * 16 + j * 4 + 3][r] = f2bf(v.w);
    }
    __syncthreads();
    const int s = r & 7;
    const int p0 = (c << 1) ^ s;
    const int p1 = ((c << 1) | 1) ^ s;
    u16* base = Wt + (size_t)(n0 + r) * 1024 + k0;
    *reinterpret_cast<short8v*>(base + p0 * 8) = *reinterpret_cast<const short8v*>(&T[r][c * 16]);
    *reinterpret_cast<short8v*>(base + p1 * 8) = *reinterpret_cast<const short8v*>(&T[r][c * 16 + 8]);
}

// ---- fused QKV GEMM (m97 structure): C(4096x1024) = Ab_z @ Wt_z^T + b_z ----
// grid (8, 32, 3), 256 thr, 128x128 tile, BK=64, gload_lds staging, swizzled reads.
__global__ __launch_bounds__(256, 3) void gemm_qkv(const u16* __restrict__ Abq,
                                                   const u16* __restrict__ Abk,
                                                   const u16* __restrict__ Abv,
                                                   const u16* __restrict__ Wtq,
                                                   const u16* __restrict__ Wtk,
                                                   const u16* __restrict__ Wtv,
                                                   const float* __restrict__ bq,
                                                   const float* __restrict__ bk,
                                                   const float* __restrict__ bv,
                                                   u16* __restrict__ dq, u16* __restrict__ dk,
                                                   u16* __restrict__ dv) {
    __shared__ u16 As[128][64];
    __shared__ u16 Bs[128][64];
    const u16* Ab; const u16* Wt; const float* bias; u16* dst;
    switch (blockIdx.z) {
        case 0: Ab = Abq; Wt = Wtq; bias = bq; dst = dq; break;
        case 1: Ab = Abk; Wt = Wtk; bias = bk; dst = dk; break;
        default: Ab = Abv; Wt = Wtv; bias = bv; dst = dv; break;
    }
    const int m0 = blockIdx.y << 7;
    const int n0 = blockIdx.x << 7;
    const int t = threadIdx.x;
    const int lane = t & 63;
    const int w = t >> 6;
    const int wr = (w >> 1) << 6;
    const int wc = (w & 1) << 6;
    const int l15 = lane & 15, lg = lane >> 4;

    const u16* ga = Ab + (size_t)(m0 + w * 32 + (lane >> 3)) * 1024 + (lane & 7) * 8;
    const u16* gb = Wt + (size_t)(n0 + w * 32 + (lane >> 3)) * 1024 + (lane & 7) * 8;

    f32x4 acc[4][4] = {};

    for (int kt = 0; kt < 16; ++kt) {
        const int k0 = kt << 6;
        if (kt) __syncthreads();
#pragma unroll
        for (int j = 0; j < 4; ++j) {
            gload16(ga + j * 8 * 1024 + k0, &As[w * 32 + j * 8][0]);
            gload16(gb + j * 8 * 1024 + k0, &Bs[w * 32 + j * 8][0]);
        }
        __syncthreads();
#pragma unroll
        for (int kk = 0; kk < 2; ++kk) {
            short8v a[4], b[4];
#pragma unroll
            for (int m = 0; m < 4; ++m) {
                const int row = wr + m * 16 + l15;
                a[m] = *reinterpret_cast<const short8v*>(&As[row][(((kk << 2) | lg) ^ (row & 7)) << 3]);
            }
#pragma unroll
            for (int n = 0; n < 4; ++n) {
                const int row = wc + n * 16 + l15;
                b[n] = *reinterpret_cast<const short8v*>(&Bs[row][(((kk << 2) | lg) ^ (row & 7)) << 3]);
            }
#pragma unroll
            for (int m = 0; m < 4; ++m)
#pragma unroll
                for (int n = 0; n < 4; ++n)
                    acc[m][n] = mfma_bf16(a[m], b[n], acc[m][n]);
        }
    }

#pragma unroll
    for (int n = 0; n < 4; ++n) {
        const int c = n0 + wc + n * 16 + l15;
        const float bvv = bias[c];
        const int h = c >> 6, d = c & 63;
#pragma unroll
        for (int m = 0; m < 4; ++m) {
#pragma unroll
            for (int r = 0; r < 4; ++r) {
                const int mi = m0 + wr + m * 16 + lg * 4 + r;
                const int s = mi >> 2, bb = mi & 3;
                dst[(size_t)(((h << 2) + bb) << 16) + (s << 6) + d] = f2bf(acc[m][n][r] + bvv);
            }
        }
    }
}

// ---- V transpose: vb[hb][s][d] -> vtb[hb][d][s] (unswizzled both sides) ----
__global__ __launch_bounds__(256) void transpose_v(const u16* __restrict__ vb,
                                                   u16* __restrict__ vtb) {
    __shared__ u16 T[64][72];
    const int hb = blockIdx.y;
    const int s0 = blockIdx.x << 6;
    const u16* src = vb + (size_t)hb * 65536;
    u16* dst = vtb + (size_t)hb * 65536;
    const int t = threadIdx.x;
    const int r = t >> 2;
    const int c = (t & 3) << 4;
    short8v v0 = *reinterpret_cast<const short8v*>(src + (size_t)(s0 + r) * 64 + c);
    short8v v1 = *reinterpret_cast<const short8v*>(src + (size_t)(s0 + r) * 64 + c + 8);
#pragma unroll
    for (int j = 0; j < 8; ++j) T[c + j][r] = (u16)v0[j];
#pragma unroll
    for (int j = 0; j < 8; ++j) T[c + 8 + j][r] = (u16)v1[j];
    __syncthreads();
    *reinterpret_cast<short8v*>(dst + (size_t)r * 1024 + s0 + c)     = *reinterpret_cast<const short8v*>(&T[r][c]);
    *reinterpret_cast<short8v*>(dst + (size_t)r * 1024 + s0 + c + 8) = *reinterpret_cast<const short8v*>(&T[r][c + 8]);
}

// ---- fused attention: 16 q-rows/block, 512 thr; ctx epilogue chunk-swizzled ----
__global__ __launch_bounds__(512, 4) void attn_kernel(const u16* __restrict__ qb,
                                                      const u16* __restrict__ kb,
                                                      const u16* __restrict__ vtb,
                                                      float* __restrict__ attn_out,
                                                      u16* __restrict__ ctxb) {
    __shared__ float Sm[16 * 1024];                          // 64 KB
    char* Sb = (char*)Sm;
    const int hb = blockIdx.y;
    const int q0 = blockIdx.x << 4;
    const int h = hb >> 2, b = hb & 3;
    const int t = threadIdx.x;
    const int lane = t & 63, w = t >> 6;
    const int l15 = lane & 15, lg = lane >> 4;

    const u16* Q = qb + (size_t)hb * 65536;
    const u16* K = kb + (size_t)hb * 65536;
    const u16* VT = vtb + (size_t)hb * 65536;

    // ---- QK^T ----
    short8v aq[2];
#pragma unroll
    for (int kh = 0; kh < 2; ++kh)
        aq[kh] = *reinterpret_cast<const short8v*>(Q + (q0 + l15) * 64 + kh * 32 + lg * 8);

#pragma unroll
    for (int n = 0; n < 8; ++n) {
        const int tcol = w * 128 + n * 16 + l15;
        f32x4 acc = {};
#pragma unroll
        for (int kh = 0; kh < 2; ++kh) {
            short8v bk = *reinterpret_cast<const short8v*>(K + tcol * 64 + kh * 32 + lg * 8);
            acc = mfma_bf16(aq[kh], bk, acc);
        }
#pragma unroll
        for (int r = 0; r < 4; ++r) {
            const int row = lg * 4 + r;
            *(float*)(Sb + (row << 12) + ((tcol << 2) ^ ((row & 7) << 4))) = acc[r] * 0.125f;
        }
    }
    __syncthreads();

    // ---- softmax on rows 2w, 2w+1 ----
#pragma unroll
    for (int rr = 0; rr < 2; ++rr) {
        const int r = w * 2 + rr;
        const int swz = (r & 7) << 4;
        f32x4 vv[4];
#pragma unroll
        for (int j = 0; j < 4; ++j)
            vv[j] = *(const f32x4*)(Sb + (r << 12) + (((lane * 4 + j * 256) << 2) ^ swz));
        float mx = -1e30f;
#pragma unroll
        for (int j = 0; j < 4; ++j)
#pragma unroll
            for (int i = 0; i < 4; ++i) mx = fmaxf(mx, vv[j][i]);
#pragma unroll
        for (int o = 1; o < 64; o <<= 1) mx = fmaxf(mx, __shfl_xor(mx, o, 64));
        float sum = 0.f;
#pragma unroll
        for (int j = 0; j < 4; ++j)
#pragma unroll
            for (int i = 0; i < 4; ++i) { vv[j][i] = __expf(vv[j][i] - mx); sum += vv[j][i]; }
#pragma unroll
        for (int o = 1; o < 64; o <<= 1) sum += __shfl_xor(sum, o, 64);
        const float inv = 1.0f / sum;
        float* grow = attn_out + (((size_t)(hb << 10) + q0 + r) << 10);
#pragma unroll
        for (int j = 0; j < 4; ++j) {
            f32x4 p = vv[j] * inv;
            *reinterpret_cast<f32x4*>(grow + lane * 4 + j * 256) = p;
            short4v pk;
            pk[0] = (short)f2bf(p[0]); pk[1] = (short)f2bf(p[1]);
            pk[2] = (short)f2bf(p[2]); pk[3] = (short)f2bf(p[3]);
            *(short4v*)(Sb + (r << 12) + (((lane * 4 + j * 256) << 1) ^ swz)) = pk;
        }
    }
    __syncthreads();

    // ---- PV: wave w covers t in [w*128, w*128+128) ----
    f32x4 cacc[4] = {};
#pragma unroll
    for (int kt = 0; kt < 4; ++kt) {
        const int kcol = w * 128 + kt * 32 + lg * 8;
        short8v ap = *(const short8v*)(Sb + (l15 << 12) + ((kcol << 1) ^ ((l15 & 7) << 4)));
#pragma unroll
        for (int n = 0; n < 4; ++n) {
            short8v bv = *reinterpret_cast<const short8v*>(VT + (size_t)(n * 16 + l15) * 1024 + kcol);
            cacc[n] = mfma_bf16(ap, bv, cacc[n]);
        }
    }
    __syncthreads();

    // ---- cross-wave partial reduce ----
    float* part = Sm;
#pragma unroll
    for (int n = 0; n < 4; ++n)
#pragma unroll
        for (int r = 0; r < 4; ++r)
            part[w * 1088 + (lg * 4 + r) * 68 + n * 16 + l15] = cacc[n][r];
    __syncthreads();
    if (t < 256) {
        const int rrow = t >> 4;
        const int c0 = (t & 15) << 2;
        f32x4 s = {};
#pragma unroll
        for (int ww = 0; ww < 8; ++ww)
            s += *reinterpret_cast<const f32x4*>(&part[ww * 1088 + rrow * 68 + c0]);
        short4v o;
        o[0] = (short)f2bf(s[0]); o[1] = (short)f2bf(s[1]);
        o[2] = (short)f2bf(s[2]); o[3] = (short)f2bf(s[3]);
        const int mi = ((q0 + rrow) << 2) + b;
        const int off = h * 64 + (((c0 >> 3) ^ (mi & 7)) << 3) + (c0 & 7);
        *reinterpret_cast<short4v*>(ctxb + (size_t)mi * 1024 + off) = o;
    }
}

// ---- out GEMM (m97 structure): out(4096x1024) = ctxb @ Wto^T + bo, fp32 out ----
// grid (8, 64), 256 thr, 64x128 tile, BK=64.
__global__ __launch_bounds__(256, 2) void gemm_out(const u16* __restrict__ ctxb,
                                                   const u16* __restrict__ Wto,
                                                   const float* __restrict__ bo,
                                                   float* __restrict__ out) {
    __shared__ u16 As[64][64];
    __shared__ u16 Bs[128][64];
    const int m0 = blockIdx.y << 6;
    const int n0 = blockIdx.x << 7;
    const int t = threadIdx.x;
    const int lane = t & 63;
    const int w = t >> 6;
    const int wr = (w >> 1) << 5;
    const int wc = (w & 1) << 6;
    const int l15 = lane & 15, lg = lane >> 4;

    const u16* ga = ctxb + (size_t)(m0 + w * 16 + (lane >> 3)) * 1024 + (lane & 7) * 8;
    const u16* gb = Wto + (size_t)(n0 + w * 32 + (lane >> 3)) * 1024 + (lane & 7) * 8;

    f32x4 acc[2][4] = {};

    for (int kt = 0; kt < 16; ++kt) {
        const int k0 = kt << 6;
        if (kt) __syncthreads();
#pragma unroll
        for (int j = 0; j < 2; ++j)
            gload16(ga + j * 8 * 1024 + k0, &As[w * 16 + j * 8][0]);
#pragma unroll
        for (int j = 0; j < 4; ++j)
            gload16(gb + j * 8 * 1024 + k0, &Bs[w * 32 + j * 8][0]);
        __syncthreads();
#pragma unroll
        for (int kk = 0; kk < 2; ++kk) {
            short8v a[2], b[4];
#pragma unroll
            for (int m = 0; m < 2; ++m) {
                const int row = wr + m * 16 + l15;
                a[m] = *reinterpret_cast<const short8v*>(&As[row][(((kk << 2) | lg) ^ (row & 7)) << 3]);
            }
#pragma unroll
            for (int n = 0; n < 4; ++n) {
                const int row = wc + n * 16 + l15;
                b[n] = *reinterpret_cast<const short8v*>(&Bs[row][(((kk << 2) | lg) ^ (row & 7)) << 3]);
            }
#pragma unroll
            for (int m = 0; m < 2; ++m)
#pragma unroll
                for (int n = 0; n < 4; ++n)
                    acc[m][n] = mfma_bf16(a[m], b[n], acc[m][n]);
        }
    }

#pragma unroll
    for (int n = 0; n < 4; ++n) {
        const int c = n0 + wc + n * 16 + l15;
        const float bvv = bo[c];
#pragma unroll
        for (int m = 0; m < 2; ++m)
#pragma unroll
            for (int r = 0; r < 4; ++r) {
                const int mi = m0 + wr + m * 16 + lg * 4 + r;
                out[(size_t)mi * 1024 + c] = acc[m][n][r] + bvv;
            }
    }
}

extern "C" void kernel_launch(void* const* d_in, const int* in_sizes, int n_in,
                              void* d_out, int out_size, void* d_ws, size_t ws_size,
                              hipStream_t stream) {
    const float* query = (const float*)d_in[0];
    const float* key   = (const float*)d_in[1];
    const float* value = (const float*)d_in[2];
    const float* Wq = (const float*)d_in[3];
    const float* bq = (const float*)d_in[4];
    const float* Wk = (const float*)d_in[5];
    const float* bk = (const float*)d_in[6];
    const float* Wv = (const float*)d_in[7];
    const float* bv = (const float*)d_in[8];
    const float* Wo = (const float*)d_in[9];
    const float* bo = (const float*)d_in[10];

    char* ws = (char*)d_ws;
    u16* Wtq  = (u16*)(ws);                       // 2 MB  swizzled
    u16* Wtk  = (u16*)(ws + ((size_t)2 << 20));
    u16* Wtv  = (u16*)(ws + ((size_t)4 << 20));
    u16* Wto  = (u16*)(ws + ((size_t)6 << 20));
    u16* qb   = (u16*)(ws + ((size_t)8 << 20));   // 8 MB [hb][s][dk] (unswizzled)
    u16* kb   = (u16*)(ws + ((size_t)16 << 20));  // 8 MB [hb][t][dk]
    u16* vb   = (u16*)(ws + ((size_t)24 << 20));  // 8 MB [hb][t][dv]
    u16* vtb  = (u16*)(ws + ((size_t)32 << 20));  // 8 MB [hb][dv][t]
    u16* ctxb = (u16*)(ws + ((size_t)24 << 20));  // aliases vb (dead); swizzled
    u16* Abq  = (u16*)(ws + ((size_t)40 << 20));  // 8 MB bf16 swizzled inputs
    u16* Abk  = (u16*)(ws + ((size_t)48 << 20));
    u16* Abv  = (u16*)(ws + ((size_t)56 << 20));

    float* out  = (float*)d_out;
    float* attn = out + (size_t)4 * 1024 * 1024;  // (H,B,S,S) fp32

    cvt_transpose_w4<<<dim3(256, 4), 256, 0, stream>>>(Wq, Wk, Wv, Wo, Wtq, Wtk, Wtv, Wto);
    cvt_inputs<<<dim3(2048, 3), 256, 0, stream>>>(query, key, value, Abq, Abk, Abv);

    gemm_qkv<<<dim3(8, 32, 3), 256, 0, stream>>>(Abq, Abk, Abv, Wtq, Wtk, Wtv,
                                                 bq, bk, bv, qb, kb, vb);

    transpose_v<<<dim3(16, 64), 256, 0, stream>>>(vb, vtb);

    attn_kernel<<<dim3(64, 64), 512, 0, stream>>>(qb, kb, vtb, attn, ctxb);

    gemm_out<<<dim3(8, 64), 256, 0, stream>>>(ctxb, Wto, bo, out);
}